// Round 1
// baseline (48.924 us; speedup 1.0000x reference)
//
#include <hip/hip_runtime.h>
#include <math.h>

#define BB 32
#define TT 50
#define HH 52
#define WW 52
#define NB 3
#define NC 80
#define CE 85          // 5 + NC
#define SP (HH*WW)     // 2704
#define NCELL (BB*NB*SP)  // 259584
#define EPSF 1e-7f

__device__ __forceinline__ float sigmoid_clamped(float z) {
    float p = 1.0f / (1.0f + expf(-z));
    return fminf(fmaxf(p, EPSF), 1.0f - EPSF);
}

__device__ __forceinline__ float bce(float p, float t) {
    return -t * logf(p) - (1.0f - t) * logf(1.0f - p);
}

// zero / init workspace
__global__ void k_init(int* winner, unsigned* clsmask, float* acc) {
    int idx = blockIdx.x * blockDim.x + threadIdx.x;
    if (idx < NCELL) winner[idx] = -1;
    if (idx < 3 * NCELL) clsmask[idx] = 0u;
    if (idx < 8) acc[idx] = 0.0f;
}

// per-target anchor matching + scatter into compact cell structures
__global__ void k_build(const float* __restrict__ xywh,
                        const int* __restrict__ cls,
                        const int* __restrict__ pi,
                        int* winner, unsigned* clsmask, float* tdata) {
    int idx = blockIdx.x * blockDim.x + threadIdx.x;
    if (idx >= BB * TT) return;
    int b = idx / TT;

    float x = xywh[idx * 4 + 0];
    float y = xywh[idx * 4 + 1];
    float w = xywh[idx * 4 + 2];
    float h = xywh[idx * 4 + 3];
    float bx = x * WW, by = y * HH, bw = w * WW, bh = h * HH;

    const float A[18] = {10,13,16,30,33,23,30,61,62,45,59,119,116,90,156,198,373,326};
    // scaled anchors: ANCHORS / (416/52) = ANCHORS * 0.125
    float best = -1.0f; int aid = 0;
    #pragma unroll
    for (int k = 0; k < 9; ++k) {
        float aw = A[2*k] * 0.125f, ah = A[2*k+1] * 0.125f;
        float inter = fminf(bw, aw) * fminf(bh, ah);
        float uni = bw * bh + aw * ah - inter;
        float iou = inter / uni;
        if (iou > best) { best = iou; aid = k; }
    }
    float aw = A[2*aid] * 0.125f, ah = A[2*aid+1] * 0.125f;
    int gx = (int)floorf(bx);
    int gy = (int)floorf(by);

    tdata[idx * 5 + 0] = bx - (float)gx;
    tdata[idx * 5 + 1] = by - (float)gy;
    tdata[idx * 5 + 2] = logf(bw / aw);
    tdata[idx * 5 + 3] = logf(bh / ah);
    tdata[idx * 5 + 4] = bw * bh / (float)(HH * WW);

    int i = *pi;
    bool valid = (aid / 3) == (2 - i);   // ANCHOR_MASK[i] = {3*(2-i), +1, +2}
    if (valid && gx >= 0 && gx < WW && gy >= 0 && gy < HH) {
        int pos = aid % 3;
        int cell = ((b * NB + pos) * HH + gy) * WW + gx;
        atomicMax(&winner[cell], idx);            // last target (largest t) wins
        int c = cls[idx];
        atomicOr(&clsmask[cell * 3 + (c >> 5)], 1u << (c & 31));
    }
}

// per-cell loss: conf for all cells; loc+cls only at positive cells
__global__ void k_loss(const float* __restrict__ pred,
                       const int* __restrict__ winner,
                       const unsigned* __restrict__ clsmask,
                       const float* __restrict__ tdata,
                       float* acc) {
    int idx = blockIdx.x * blockDim.x + threadIdx.x;
    float conf = 0.0f;
    if (idx < NCELL) {
        int ba = idx / SP;          // b*3 + a
        int sp = idx % SP;          // gy*W + gx
        const float* pc = pred + (size_t)ba * CE * SP + sp;
        float p4 = sigmoid_clamped(pc[4 * SP]);
        int wn = winner[idx];
        if (wn >= 0) {
            conf = -logf(p4);       // bce(p4, 1)
            const float* td = tdata + wn * 5;
            float scale = 2.0f - td[4];
            float z0 = pc[0], z1 = pc[SP], z2 = pc[2 * SP], z3 = pc[3 * SP];
            float lx = bce(sigmoid_clamped(z0), td[0]) * scale;
            float ly = bce(sigmoid_clamped(z1), td[1]) * scale;
            float dw = z2 - td[2];
            float dh = z3 - td[3];
            float lw = dw * dw * scale;
            float lh = dh * dh * scale;
            unsigned m0 = clsmask[idx * 3 + 0];
            unsigned m1 = clsmask[idx * 3 + 1];
            unsigned m2 = clsmask[idx * 3 + 2];
            float cls_s = 0.0f;
            #pragma unroll
            for (int c = 0; c < NC; ++c) {
                float pp = sigmoid_clamped(pc[(5 + c) * SP]);
                unsigned bit = (c < 32) ? ((m0 >> c) & 1u)
                             : (c < 64) ? ((m1 >> (c - 32)) & 1u)
                                        : ((m2 >> (c - 64)) & 1u);
                cls_s += bce(pp, bit ? 1.0f : 0.0f);
            }
            atomicAdd(&acc[1], lx);
            atomicAdd(&acc[2], ly);
            atomicAdd(&acc[3], lw);
            atomicAdd(&acc[4], lh);
            atomicAdd(&acc[5], cls_s);
            atomicAdd(&acc[6], 1.0f);
        } else {
            conf = -logf(1.0f - p4);  // bce(p4, 0)
        }
    }
    // block-reduce conf: wave64 shuffle then LDS
    #pragma unroll
    for (int off = 32; off > 0; off >>= 1)
        conf += __shfl_down(conf, off);
    __shared__ float sc;
    if (threadIdx.x == 0) sc = 0.0f;
    __syncthreads();
    if ((threadIdx.x & 63) == 0) atomicAdd(&sc, conf);
    __syncthreads();
    if (threadIdx.x == 0) atomicAdd(&acc[0], sc);
}

__global__ void k_final(const float* __restrict__ acc,
                        const int* __restrict__ pi,
                        float* __restrict__ out) {
    float pos_num = acc[6];
    float den = fmaxf(pos_num, 1.0f);
    float loc = (acc[1] + acc[2] + acc[3] + acc[4]) / den * 0.1f;
    float cls = acc[5] / (den * (float)NC);
    int i = *pi;
    float bal = (i == 0) ? 0.4f : (i == 1) ? 1.0f : 4.0f;
    float conf = acc[0] / (float)NCELL * bal;
    bool has = pos_num > 0.0f;
    float total = (has ? (loc * 0.05f + cls * 0.5f) : 0.0f) + conf;
    out[0] = total;
    out[1] = conf;
    out[2] = has ? loc : 0.0f;
    out[3] = has ? cls : 0.0f;
}

extern "C" void kernel_launch(void* const* d_in, const int* in_sizes, int n_in,
                              void* d_out, int out_size, void* d_ws, size_t ws_size,
                              hipStream_t stream) {
    const int*   pi   = (const int*)d_in[0];
    const float* pred = (const float*)d_in[1];
    const float* xywh = (const float*)d_in[2];
    const int*   cls  = (const int*)d_in[3];
    float* out = (float*)d_out;

    char* ws = (char*)d_ws;
    int*      winner  = (int*)ws;                                   // NCELL ints
    unsigned* clsmask = (unsigned*)(ws + (size_t)NCELL * 4);        // 3*NCELL uints
    float*    tdata   = (float*)(ws + (size_t)NCELL * 16);          // B*T*5 floats
    float*    acc     = (float*)(ws + (size_t)NCELL * 16 + BB*TT*5*4); // 8 floats

    k_init <<<(3 * NCELL + 255) / 256, 256, 0, stream>>>(winner, clsmask, acc);
    k_build<<<(BB * TT + 255) / 256, 256, 0, stream>>>(xywh, cls, pi, winner, clsmask, tdata);
    k_loss <<<NCELL / 256, 256, 0, stream>>>(pred, winner, clsmask, tdata, acc);
    k_final<<<1, 1, 0, stream>>>(acc, pi, out);
}